// Round 9
// baseline (66896.729 us; speedup 1.0000x reference)
//
#include <hip/hip_runtime.h>
#include <math.h>

// VanillaRNN B=256,T=512,H=1024,O=10 — bit-exact replication of reference CPU
// fp32 trajectory. Decoded arithmetic (R5-R7 oracle): kc=512 panels, no-FMA
// gemm chains (__fmul_rn/__fadd_rn, k ascending, panels joined in order),
// tanh = clamp ±7.99881172180175781 + fmaf Horner + IEEE div, no-FMA xp.
//
// R9: occupancy restructure. 512 WGs (cooperative) = 32 row-groups x 16
// col-tiles; WG = 8 rows x 64 cols, 256 thr; thread = 2 rows x 1 col.
// LDS 64 KB/WG (32K h + 32K W dbuf) -> 2 WGs/CU, 2 waves/SIMD: stalls of one
// row-group overlap MACs of the other. Panels processed sequentially
// (identical chain bits). Row-group's 16 WGs pinned to one XCD (bid%8).

#define HH 1024
#define TT 512
#define BB 256
#define OO 10
#define NG 32      // row groups
#define NCT 16     // col tiles per group
#define RPG 8      // rows per group
#define CPT 64     // cols per tile
#define NTH 256

__device__ __forceinline__ float tanh_ref(float x) {
    const float kClamp = 7.99881172180175781f;
    float xc = fminf(fmaxf(x, -kClamp), kClamp);
    float x2 = __fmul_rn(xc, xc);
    float p = -2.76076847742355e-16f;
    p = fmaf(x2, p,  2.00018790482477e-13f);
    p = fmaf(x2, p, -8.60467152213735e-11f);
    p = fmaf(x2, p,  5.12229709037114e-08f);
    p = fmaf(x2, p,  1.48572235717979e-05f);
    p = fmaf(x2, p,  6.37261928875436e-04f);
    p = fmaf(x2, p,  4.89352455891786e-03f);
    p = __fmul_rn(xc, p);
    float q = 1.19825839466702e-06f;
    q = fmaf(x2, q, 1.18534705686654e-04f);
    q = fmaf(x2, q, 2.26843463243900e-03f);
    q = fmaf(x2, q, 4.89352518554385e-03f);
    float r = __fdiv_rn(p, q);
    return (fabsf(x) < 0.0004f) ? x : r;
}

#define MACC(acc, hv, wv) acc = __fadd_rn(acc, __fmul_rn(hv, wv))

__global__ void __launch_bounds__(NTH, 2) rnn_persist(
    const float* __restrict__ x, const float* __restrict__ Whx,
    const float* __restrict__ Whh, const float* __restrict__ Wph,
    const float* __restrict__ bh, const float* __restrict__ bo,
    float* __restrict__ out, float* __restrict__ ws)
{
    __shared__ float h_lds[RPG][HH];        // 32 KB
    __shared__ float wbuf[2][64][CPT];      // 32 KB: [dbuf][k][j]

    const int bid  = blockIdx.x;
    // XCD-pinned mapping: all 16 WGs of a row-group share bid%8 (one XCD).
    const int xcd  = bid & 7;
    const int rest = bid >> 3;          // 0..63
    const int ct   = rest & 15;         // col tile 0..15
    const int gg   = rest >> 4;         // 0..3
    const int g    = xcd * 4 + gg;      // row group 0..31

    const int tid  = threadIdx.x;
    const int w    = tid >> 6;          // wave 0..3
    const int lane = tid & 63;
    const int r0   = g * RPG;           // first global row of group
    const int rw   = w * 2;             // wave's first local row (2 rows/wave)
    const int j0   = ct * CPT;
    const int j    = j0 + lane;

    float* hA = ws;                     // [256][1024]
    float* hB = ws + (BB * HH);
    int*   ctr = (int*)(ws + 2 * BB * HH);  // [32], memset 0 pre-launch

    const float whx_j = Whx[j];
    const float bh_j  = bh[j];

    // ---- zero-init hA slice, group sync ----
    hA[(r0 + rw + 0) * HH + j] = 0.0f;
    hA[(r0 + rw + 1) * HH + j] = 0.0f;
    __threadfence();
    __syncthreads();
    if (tid == 0) {
        __hip_atomic_fetch_add(&ctr[g], 1, __ATOMIC_RELEASE, __HIP_MEMORY_SCOPE_AGENT);
        while (__hip_atomic_load(&ctr[g], __ATOMIC_ACQUIRE, __HIP_MEMORY_SCOPE_AGENT) < NCT)
            __builtin_amdgcn_s_sleep(2);
    }
    __syncthreads();
    __threadfence();

    float4 wreg[4];

    // chunk kb (0..15) = W[kb*64 .. kb*64+64)[j0 .. j0+64)   (16 KB)
    #define LOAD_CHUNK(kb_)                                                     \
        {   const int kb__ = (kb_);                                             \
            _Pragma("unroll")                                                   \
            for (int i = 0; i < 4; ++i) {                                       \
                const int qq = tid + i * NTH;                                   \
                wreg[i] = *((const float4*)(Whh +                               \
                    (size_t)(kb__ * 64 + (qq >> 4)) * HH + j0) + (qq & 15));    \
            }                                                                   \
        }
    #define STORE_CHUNK(buf_)                                                   \
        {   float4* wdst = (float4*)&wbuf[buf_][0][0];                          \
            _Pragma("unroll")                                                   \
            for (int i = 0; i < 4; ++i) wdst[tid + i * NTH] = wreg[i];          \
        }

    for (int t = 0; t < TT; ++t) {
        const float* hsrc = (t & 1) ? hB : hA;
        float*       hdst = (t & 1) ? hA : hB;

        const float xv0 = x[(r0 + rw + 0) * TT + t];
        const float xv1 = x[(r0 + rw + 1) * TT + t];

        // stage h rows (32 KB) global -> LDS: 8 float4 per thread
        {
            const float4* src = (const float4*)(hsrc + (size_t)r0 * HH);
            float4* dst = (float4*)&h_lds[0][0];
            #pragma unroll
            for (int i = 0; i < 8; i += 4) {
                float4 t0 = src[tid + (i + 0) * NTH];
                float4 t1 = src[tid + (i + 1) * NTH];
                float4 t2 = src[tid + (i + 2) * NTH];
                float4 t3 = src[tid + (i + 3) * NTH];
                dst[tid + (i + 0) * NTH] = t0;
                dst[tid + (i + 1) * NTH] = t1;
                dst[tid + (i + 2) * NTH] = t2;
                dst[tid + (i + 3) * NTH] = t3;
            }
        }
        LOAD_CHUNK(0)
        STORE_CHUNK(0)
        __syncthreads();

        // panel chains: a = panel0 (k 0..511), b = panel1 (k 512..1023)
        float a0 = 0.f, a1 = 0.f, b0 = 0.f, b1 = 0.f;

        #pragma unroll 1
        for (int kb = 0; kb < 16; ++kb) {
            const int buf = kb & 1;
            if (kb < 15) LOAD_CHUNK(kb + 1)

            float* accL = (kb < 8) ? &a0 : &b0;
            float* accR = (kb < 8) ? &a1 : &b1;
            float sL = *accL, sR = *accR;
            const int kOff = kb * 64;
            #pragma unroll 4
            for (int k4 = 0; k4 < 16; ++k4) {
                const float4 h0 = *(const float4*)&h_lds[rw + 0][kOff + k4 * 4];
                const float4 h1 = *(const float4*)&h_lds[rw + 1][kOff + k4 * 4];
                const float w0 = wbuf[buf][k4 * 4 + 0][lane];
                const float w1 = wbuf[buf][k4 * 4 + 1][lane];
                const float w2 = wbuf[buf][k4 * 4 + 2][lane];
                const float w3 = wbuf[buf][k4 * 4 + 3][lane];
                // k ascending — chain order is the correctness contract
                MACC(sL, h0.x, w0); MACC(sR, h1.x, w0);
                MACC(sL, h0.y, w1); MACC(sR, h1.y, w1);
                MACC(sL, h0.z, w2); MACC(sR, h1.z, w2);
                MACC(sL, h0.w, w3); MACC(sR, h1.w, w3);
            }
            *accL = sL; *accR = sR;

            if (kb < 15) {
                __syncthreads();          // readers of buf done
                STORE_CHUNK(buf ^ 1)
                __syncthreads();          // next chunk visible
            }
        }

        // join panels (p0 then p1), xp, z, tanh, store
        {
            const float m0 = __fadd_rn(a0, b0);
            const float m1 = __fadd_rn(a1, b1);
            const float xp0 = __fadd_rn(__fmul_rn(xv0, whx_j), bh_j);
            const float xp1 = __fadd_rn(__fmul_rn(xv1, whx_j), bh_j);
            hdst[(r0 + rw + 0) * HH + j] = tanh_ref(__fadd_rn(xp0, m0));
            hdst[(r0 + rw + 1) * HH + j] = tanh_ref(__fadd_rn(xp1, m1));
        }

        // row-group sync (monotonic counter, agent scope)
        __threadfence();
        __syncthreads();
        if (tid == 0) {
            __hip_atomic_fetch_add(&ctr[g], 1, __ATOMIC_RELEASE, __HIP_MEMORY_SCOPE_AGENT);
            const int target = NCT * (t + 2);
            while (__hip_atomic_load(&ctr[g], __ATOMIC_ACQUIRE, __HIP_MEMORY_SCOPE_AGENT) < target)
                __builtin_amdgcn_s_sleep(2);
        }
        __syncthreads();
        __threadfence();
    }

    // ---- epilogue: out = h_final @ Wph + bo (h_final in hA; TT even) ----
    if (ct == 0) {
        #pragma unroll 1
        for (int r = 0; r < 2; ++r) {
            const int row = r0 + rw + r;
            #pragma unroll 1
            for (int o = 0; o < OO; ++o) {
                float v = 0.0f;
                #pragma unroll
                for (int m = 0; m < HH / 64; ++m) {
                    const int k = lane + (m << 6);
                    v = fmaf(hA[row * HH + k], Wph[k * OO + o], v);
                }
                #pragma unroll
                for (int s = 32; s > 0; s >>= 1) v += __shfl_down(v, s, 64);
                if (lane == 0) out[row * OO + o] = v + bo[o];
            }
        }
    }
}

extern "C" void kernel_launch(void* const* d_in, const int* in_sizes, int n_in,
                              void* d_out, int out_size, void* d_ws, size_t ws_size,
                              hipStream_t stream) {
    const float* x   = (const float*)d_in[0];
    const float* Whx = (const float*)d_in[1];
    const float* Whh = (const float*)d_in[2];
    const float* Wph = (const float*)d_in[3];
    const float* bh  = (const float*)d_in[4];
    const float* bo  = (const float*)d_in[5];
    float* out = (float*)d_out;
    float* ws  = (float*)d_ws;

    // reset row-group counters (deterministic across graph replays)
    hipMemsetAsync((char*)d_ws + (size_t)2 * BB * HH * 4, 0, NG * sizeof(int), stream);

    void* args[] = {(void*)&x, (void*)&Whx, (void*)&Whh, (void*)&Wph,
                    (void*)&bh, (void*)&bo, (void*)&out, (void*)&ws};
    hipLaunchCooperativeKernel((void*)rnn_persist, dim3(NG * NCT), dim3(NTH),
                               args, 0, stream);
}

// Round 13
// 60152.527 us; speedup vs baseline: 1.1121x; 1.1121x over previous
//
#include <hip/hip_runtime.h>
#include <math.h>

// VanillaRNN B=256,T=512,H=1024,O=10 — bit-exact replication of reference CPU
// fp32 trajectory. Decoded arithmetic (R5-R7 oracle): kc=512 panels, no-FMA
// chains (__fmul_rn/__fadd_rn, k ascending, panels joined in order), tanh =
// clamp ±7.99881172180175781 + fmaf Horner + IEEE div, no-FMA xp.
//
// R13 = R9 (PASSING, 66.9 ms) with EXACTLY ONE change: W LDS staging deleted
// (was 2.4e9 bank-conflict cycles + 30 barriers/step); W read directly from
// global, coalesced 64x4B per k-row, L1/L2-served (unique W per XCD ~4MB/step
// = L2-resident). Everything else byte-identical to R9: 512 WGs x 256 thr
// (2/CU), WG = 8 rows x 64 cols, thread = 2 rows x 1 col, panels sequential
// (a=k<512, b=k>=512, m=fadd(a,b)), h staged in LDS (broadcast reads),
// R9 sync macro/mapping/epilogue verbatim.
// R11/R12 post-mortem: identical wrong output under 2 different XCD mappings
// => deterministic bug in their rewritten body, NOT coherence; bisect from
// the passing side instead.

#define HH 1024
#define TT 512
#define BB 256
#define OO 10
#define NG 32      // row groups
#define NCT 16     // col tiles per group
#define RPG 8      // rows per group
#define CPT 64     // cols per tile
#define NTH 256

__device__ __forceinline__ float tanh_ref(float x) {
    const float kClamp = 7.99881172180175781f;
    float xc = fminf(fmaxf(x, -kClamp), kClamp);
    float x2 = __fmul_rn(xc, xc);
    float p = -2.76076847742355e-16f;
    p = fmaf(x2, p,  2.00018790482477e-13f);
    p = fmaf(x2, p, -8.60467152213735e-11f);
    p = fmaf(x2, p,  5.12229709037114e-08f);
    p = fmaf(x2, p,  1.48572235717979e-05f);
    p = fmaf(x2, p,  6.37261928875436e-04f);
    p = fmaf(x2, p,  4.89352455891786e-03f);
    p = __fmul_rn(xc, p);
    float q = 1.19825839466702e-06f;
    q = fmaf(x2, q, 1.18534705686654e-04f);
    q = fmaf(x2, q, 2.26843463243900e-03f);
    q = fmaf(x2, q, 4.89352518554385e-03f);
    float r = __fdiv_rn(p, q);
    return (fabsf(x) < 0.0004f) ? x : r;
}

#define MACC(acc, hv, wv) acc = __fadd_rn(acc, __fmul_rn(hv, wv))

__global__ void __launch_bounds__(NTH, 2) rnn_persist(
    const float* __restrict__ x, const float* __restrict__ Whx,
    const float* __restrict__ Whh, const float* __restrict__ Wph,
    const float* __restrict__ bh, const float* __restrict__ bo,
    float* __restrict__ out, float* __restrict__ ws)
{
    __shared__ float h_lds[RPG][HH];        // 32 KB (W staging removed)

    const int bid  = blockIdx.x;
    const int xcd  = bid & 7;
    const int rest = bid >> 3;          // 0..63
    const int ct   = rest & 15;         // col tile 0..15
    const int gg   = rest >> 4;         // 0..3
    const int g    = xcd * 4 + gg;      // row group 0..31

    const int tid  = threadIdx.x;
    const int w    = tid >> 6;          // wave 0..3
    const int lane = tid & 63;
    const int r0   = g * RPG;           // first global row of group
    const int rw   = w * 2;             // wave's first local row (2 rows/wave)
    const int j0   = ct * CPT;
    const int j    = j0 + lane;

    float* hA = ws;                     // [256][1024]
    float* hB = ws + (BB * HH);
    int*   ctr = (int*)(ws + 2 * BB * HH);  // [32], memset 0 pre-launch

    const float whx_j = Whx[j];
    const float bh_j  = bh[j];

    // ---- zero-init hA slice, group sync (R9 verbatim) ----
    hA[(r0 + rw + 0) * HH + j] = 0.0f;
    hA[(r0 + rw + 1) * HH + j] = 0.0f;
    __threadfence();
    __syncthreads();
    if (tid == 0) {
        __hip_atomic_fetch_add(&ctr[g], 1, __ATOMIC_RELEASE, __HIP_MEMORY_SCOPE_AGENT);
        while (__hip_atomic_load(&ctr[g], __ATOMIC_ACQUIRE, __HIP_MEMORY_SCOPE_AGENT) < NCT)
            __builtin_amdgcn_s_sleep(2);
    }
    __syncthreads();
    __threadfence();

    for (int t = 0; t < TT; ++t) {
        const float* hsrc = (t & 1) ? hB : hA;
        float*       hdst = (t & 1) ? hA : hB;

        const float xv0 = x[(r0 + rw + 0) * TT + t];
        const float xv1 = x[(r0 + rw + 1) * TT + t];

        // stage h rows (32 KB) global -> LDS: 8 float4 per thread (R9 verbatim)
        {
            const float4* src = (const float4*)(hsrc + (size_t)r0 * HH);
            float4* dst = (float4*)&h_lds[0][0];
            #pragma unroll
            for (int i = 0; i < 8; i += 4) {
                float4 t0 = src[tid + (i + 0) * NTH];
                float4 t1 = src[tid + (i + 1) * NTH];
                float4 t2 = src[tid + (i + 2) * NTH];
                float4 t3 = src[tid + (i + 3) * NTH];
                dst[tid + (i + 0) * NTH] = t0;
                dst[tid + (i + 1) * NTH] = t1;
                dst[tid + (i + 2) * NTH] = t2;
                dst[tid + (i + 3) * NTH] = t3;
            }
        }
        __syncthreads();   // h_lds ready

        // panel chains: a = panel0 (k 0..511), b = panel1 (k 512..1023)
        float a0 = 0.f, a1 = 0.f, b0 = 0.f, b1 = 0.f;
        const float* wp = Whh + j;      // W[k][j], k advancing

        #pragma unroll 1
        for (int kb = 0; kb < 16; ++kb) {
            float* accL = (kb < 8) ? &a0 : &b0;
            float* accR = (kb < 8) ? &a1 : &b1;
            float sL = *accL, sR = *accR;
            const int kOff = kb * 64;
            #pragma unroll 4
            for (int k4 = 0; k4 < 16; ++k4) {
                const float4 h0 = *(const float4*)&h_lds[rw + 0][kOff + k4 * 4];
                const float4 h1 = *(const float4*)&h_lds[rw + 1][kOff + k4 * 4];
                const float w0 = wp[0];
                const float w1 = wp[HH];
                const float w2 = wp[2 * HH];
                const float w3 = wp[3 * HH];
                wp += 4 * HH;
                // k ascending — chain order is the correctness contract
                MACC(sL, h0.x, w0); MACC(sR, h1.x, w0);
                MACC(sL, h0.y, w1); MACC(sR, h1.y, w1);
                MACC(sL, h0.z, w2); MACC(sR, h1.z, w2);
                MACC(sL, h0.w, w3); MACC(sR, h1.w, w3);
            }
            *accL = sL; *accR = sR;
        }

        // join panels (p0 then p1), xp, z, tanh, store (R9 verbatim)
        {
            const float m0 = __fadd_rn(a0, b0);
            const float m1 = __fadd_rn(a1, b1);
            const float xp0 = __fadd_rn(__fmul_rn(xv0, whx_j), bh_j);
            const float xp1 = __fadd_rn(__fmul_rn(xv1, whx_j), bh_j);
            hdst[(r0 + rw + 0) * HH + j] = tanh_ref(__fadd_rn(xp0, m0));
            hdst[(r0 + rw + 1) * HH + j] = tanh_ref(__fadd_rn(xp1, m1));
        }

        // row-group sync (monotonic counter, agent scope — R9 verbatim)
        __threadfence();
        __syncthreads();
        if (tid == 0) {
            __hip_atomic_fetch_add(&ctr[g], 1, __ATOMIC_RELEASE, __HIP_MEMORY_SCOPE_AGENT);
            const int target = NCT * (t + 2);
            while (__hip_atomic_load(&ctr[g], __ATOMIC_ACQUIRE, __HIP_MEMORY_SCOPE_AGENT) < target)
                __builtin_amdgcn_s_sleep(2);
        }
        __syncthreads();
        __threadfence();
    }

    // ---- epilogue: out = h_final @ Wph + bo (h_final in hA; R9 verbatim) ----
    if (ct == 0) {
        #pragma unroll 1
        for (int r = 0; r < 2; ++r) {
            const int row = r0 + rw + r;
            #pragma unroll 1
            for (int o = 0; o < OO; ++o) {
                float v = 0.0f;
                #pragma unroll
                for (int m = 0; m < HH / 64; ++m) {
                    const int k = lane + (m << 6);
                    v = fmaf(hA[(size_t)row * HH + k], Wph[k * OO + o], v);
                }
                #pragma unroll
                for (int s = 32; s > 0; s >>= 1) v += __shfl_down(v, s, 64);
                if (lane == 0) out[row * OO + o] = v + bo[o];
            }
        }
    }
}

extern "C" void kernel_launch(void* const* d_in, const int* in_sizes, int n_in,
                              void* d_out, int out_size, void* d_ws, size_t ws_size,
                              hipStream_t stream) {
    const float* x   = (const float*)d_in[0];
    const float* Whx = (const float*)d_in[1];
    const float* Whh = (const float*)d_in[2];
    const float* Wph = (const float*)d_in[3];
    const float* bh  = (const float*)d_in[4];
    const float* bo  = (const float*)d_in[5];
    float* out = (float*)d_out;
    float* ws  = (float*)d_ws;

    // reset row-group counters (R9 verbatim)
    hipMemsetAsync((char*)d_ws + (size_t)2 * BB * HH * 4, 0, NG * sizeof(int), stream);

    void* args[] = {(void*)&x, (void*)&Whx, (void*)&Whh, (void*)&Wph,
                    (void*)&bh, (void*)&bo, (void*)&out, (void*)&ws};
    hipLaunchCooperativeKernel((void*)rnn_persist, dim3(NG * NCT), dim3(NTH),
                               args, 0, stream);
}

// Round 14
// 34789.478 us; speedup vs baseline: 1.9229x; 1.7290x over previous
//
#include <hip/hip_runtime.h>
#include <math.h>

// VanillaRNN B=256,T=512,H=1024,O=10 — bit-exact replication of reference CPU
// fp32 trajectory. Decoded arithmetic (R5-R7 oracle): kc=512 panels, no-FMA
// chains (__fmul_rn/__fadd_rn, k ascending, panels joined in order), tanh =
// clamp ±7.99881172180175781 + fmaf Horner + IEEE div, no-FMA xp.
//
// R14: W-panel0 persistent in LDS (128 KB, loaded ONCE — R8 proved 144 KB
// static LDS works), panel1 W direct-global (R13-proven), h via wave-uniform
// float4 loads. 256 WGs (1/CU) = 16 ct x 16 rg; WG = 16 rows x 64 cols;
// thread = 4 rows x 1 col (32 MACC per 8 w-accesses — 2x R13's ratio).
// Panels fused in one k-loop (independent chains; order preserved per panel).
// R13 sync verbatim (fan-in 16, XCD-local groups: bid%8 == g>>1).

#define HH 1024
#define TT 512
#define BB 256
#define OO 10
#define NG 16      // row groups (16 rows)
#define NCT 16     // col tiles (64 cols)
#define NTH 256
#define KH 512     // panel size

__device__ __forceinline__ float tanh_ref(float x) {
    const float kClamp = 7.99881172180175781f;
    float xc = fminf(fmaxf(x, -kClamp), kClamp);
    float x2 = __fmul_rn(xc, xc);
    float p = -2.76076847742355e-16f;
    p = fmaf(x2, p,  2.00018790482477e-13f);
    p = fmaf(x2, p, -8.60467152213735e-11f);
    p = fmaf(x2, p,  5.12229709037114e-08f);
    p = fmaf(x2, p,  1.48572235717979e-05f);
    p = fmaf(x2, p,  6.37261928875436e-04f);
    p = fmaf(x2, p,  4.89352455891786e-03f);
    p = __fmul_rn(xc, p);
    float q = 1.19825839466702e-06f;
    q = fmaf(x2, q, 1.18534705686654e-04f);
    q = fmaf(x2, q, 2.26843463243900e-03f);
    q = fmaf(x2, q, 4.89352518554385e-03f);
    float r = __fdiv_rn(p, q);
    return (fabsf(x) < 0.0004f) ? x : r;
}

#define MACC(acc, hv, wv) acc = __fadd_rn(acc, __fmul_rn(hv, wv))

__global__ void __launch_bounds__(NTH, 1) rnn_persist(
    const float* __restrict__ x, const float* __restrict__ Whx,
    const float* __restrict__ Whh, const float* __restrict__ Wph,
    const float* __restrict__ bh, const float* __restrict__ bo,
    float* __restrict__ out, float* __restrict__ ws)
{
    __shared__ float wlds[KH][64];      // 128 KB: W[k<512][j0..j0+64)

    const int bid  = blockIdx.x;        // 0..255
    const int ct   = (bid >> 3) & 15;                 // col tile
    const int g    = ((bid & 7) << 1) | (bid >> 7);   // row group; bid%8 == g>>1
    const int tid  = threadIdx.x;
    const int w    = tid >> 6;          // wave 0..3
    const int lane = tid & 63;
    const int j0   = ct * 64;
    const int j    = j0 + lane;         // this thread's column
    const int r0w  = g * 16 + w * 4;    // this wave's first row

    float* hAbuf = ws;                  // [256][1024]
    float* hBbuf = ws + (BB * HH);
    int*   ctr   = (int*)(ws + 2 * BB * HH);  // [16], memset 0 pre-launch

    const float whx_j = Whx[j];
    const float bh_j  = bh[j];

    // ---- one-time W panel0 preload: 8192 float4 slots, coalesced ----
    #pragma unroll
    for (int i = 0; i < 32; ++i) {
        const int s = tid + i * NTH;     // 0..8191
        const int k = s >> 4;            // 0..511
        const int c = s & 15;            // float4 within 64-col row
        ((float4*)wlds)[s] = ((const float4*)(Whh + (size_t)k * HH + j0))[c];
    }

    // ---- zero-init hA rows, then group sync (R13 verbatim; also fences wlds) ----
    #pragma unroll
    for (int r = 0; r < 4; ++r)
        hAbuf[(size_t)(r0w + r) * HH + j] = 0.0f;
    __threadfence();
    __syncthreads();
    if (tid == 0) {
        __hip_atomic_fetch_add(&ctr[g], 1, __ATOMIC_RELEASE, __HIP_MEMORY_SCOPE_AGENT);
        while (__hip_atomic_load(&ctr[g], __ATOMIC_ACQUIRE, __HIP_MEMORY_SCOPE_AGENT) < NCT)
            __builtin_amdgcn_s_sleep(2);
    }
    __syncthreads();
    __threadfence();

    for (int t = 0; t < TT; ++t) {
        const float* hsrc = (t & 1) ? hBbuf : hAbuf;
        float*       hdst = (t & 1) ? hAbuf : hBbuf;

        const float* h0p = hsrc + (size_t)(r0w + 0) * HH;
        const float* h1p = hsrc + (size_t)(r0w + 1) * HH;
        const float* h2p = hsrc + (size_t)(r0w + 2) * HH;
        const float* h3p = hsrc + (size_t)(r0w + 3) * HH;
        const float* wp1 = Whh + (size_t)KH * HH + j;   // panel1 W[512+k][j]

        float a0 = 0.f, a1 = 0.f, a2 = 0.f, a3 = 0.f;   // panel0 chains
        float b0 = 0.f, b1 = 0.f, b2 = 0.f, b3 = 0.f;   // panel1 chains

        #pragma unroll 2
        for (int k4 = 0; k4 < KH; k4 += 4) {
            // h for both panels, wave-uniform float4 broadcasts
            const float4 ha0 = *(const float4*)(h0p + k4);
            const float4 ha1 = *(const float4*)(h1p + k4);
            const float4 ha2 = *(const float4*)(h2p + k4);
            const float4 ha3 = *(const float4*)(h3p + k4);
            const float4 hb0 = *(const float4*)(h0p + KH + k4);
            const float4 hb1 = *(const float4*)(h1p + KH + k4);
            const float4 hb2 = *(const float4*)(h2p + KH + k4);
            const float4 hb3 = *(const float4*)(h3p + KH + k4);
            // panel0 W from LDS (2-way aliasing = free)
            const float w0 = wlds[k4 + 0][lane];
            const float w1 = wlds[k4 + 1][lane];
            const float w2 = wlds[k4 + 2][lane];
            const float w3 = wlds[k4 + 3][lane];
            // panel1 W from global (coalesced 256B per k-row)
            const float v0 = wp1[0];
            const float v1 = wp1[HH];
            const float v2 = wp1[2 * HH];
            const float v3 = wp1[3 * HH];
            wp1 += 4 * HH;
            // k ascending per panel — chain order is the correctness contract
            MACC(a0, ha0.x, w0); MACC(a1, ha1.x, w0); MACC(a2, ha2.x, w0); MACC(a3, ha3.x, w0);
            MACC(b0, hb0.x, v0); MACC(b1, hb1.x, v0); MACC(b2, hb2.x, v0); MACC(b3, hb3.x, v0);
            MACC(a0, ha0.y, w1); MACC(a1, ha1.y, w1); MACC(a2, ha2.y, w1); MACC(a3, ha3.y, w1);
            MACC(b0, hb0.y, v1); MACC(b1, hb1.y, v1); MACC(b2, hb2.y, v1); MACC(b3, hb3.y, v1);
            MACC(a0, ha0.z, w2); MACC(a1, ha1.z, w2); MACC(a2, ha2.z, w2); MACC(a3, ha3.z, w2);
            MACC(b0, hb0.z, v2); MACC(b1, hb1.z, v2); MACC(b2, hb2.z, v2); MACC(b3, hb3.z, v2);
            MACC(a0, ha0.w, w3); MACC(a1, ha1.w, w3); MACC(a2, ha2.w, w3); MACC(a3, ha3.w, w3);
            MACC(b0, hb0.w, v3); MACC(b1, hb1.w, v3); MACC(b2, hb2.w, v3); MACC(b3, hb3.w, v3);
        }

        // join panels (p0 then p1), xp, z, tanh, store (contract order)
        {
            const float m0 = __fadd_rn(a0, b0);
            const float m1 = __fadd_rn(a1, b1);
            const float m2 = __fadd_rn(a2, b2);
            const float m3 = __fadd_rn(a3, b3);
            const float xv0 = x[(r0w + 0) * TT + t];
            const float xv1 = x[(r0w + 1) * TT + t];
            const float xv2 = x[(r0w + 2) * TT + t];
            const float xv3 = x[(r0w + 3) * TT + t];
            hdst[(size_t)(r0w + 0) * HH + j] =
                tanh_ref(__fadd_rn(__fadd_rn(__fmul_rn(xv0, whx_j), bh_j), m0));
            hdst[(size_t)(r0w + 1) * HH + j] =
                tanh_ref(__fadd_rn(__fadd_rn(__fmul_rn(xv1, whx_j), bh_j), m1));
            hdst[(size_t)(r0w + 2) * HH + j] =
                tanh_ref(__fadd_rn(__fadd_rn(__fmul_rn(xv2, whx_j), bh_j), m2));
            hdst[(size_t)(r0w + 3) * HH + j] =
                tanh_ref(__fadd_rn(__fadd_rn(__fmul_rn(xv3, whx_j), bh_j), m3));
        }

        // row-group sync (monotonic counter, agent scope — R13 verbatim)
        __threadfence();
        __syncthreads();
        if (tid == 0) {
            __hip_atomic_fetch_add(&ctr[g], 1, __ATOMIC_RELEASE, __HIP_MEMORY_SCOPE_AGENT);
            const int target = NCT * (t + 2);
            while (__hip_atomic_load(&ctr[g], __ATOMIC_ACQUIRE, __HIP_MEMORY_SCOPE_AGENT) < target)
                __builtin_amdgcn_s_sleep(2);
        }
        __syncthreads();
        __threadfence();
    }

    // ---- epilogue: out = h_final @ Wph + bo (h_final in hAbuf; TT even) ----
    if (ct == 0) {
        #pragma unroll 1
        for (int r = 0; r < 4; ++r) {
            const int row = r0w + r;
            #pragma unroll 1
            for (int o = 0; o < OO; ++o) {
                float v = 0.0f;
                #pragma unroll
                for (int m = 0; m < HH / 64; ++m) {
                    const int k = lane + (m << 6);
                    v = fmaf(hAbuf[(size_t)row * HH + k], Wph[k * OO + o], v);
                }
                #pragma unroll
                for (int s = 32; s > 0; s >>= 1) v += __shfl_down(v, s, 64);
                if (lane == 0) out[row * OO + o] = v + bo[o];
            }
        }
    }
}

extern "C" void kernel_launch(void* const* d_in, const int* in_sizes, int n_in,
                              void* d_out, int out_size, void* d_ws, size_t ws_size,
                              hipStream_t stream) {
    const float* x   = (const float*)d_in[0];
    const float* Whx = (const float*)d_in[1];
    const float* Whh = (const float*)d_in[2];
    const float* Wph = (const float*)d_in[3];
    const float* bh  = (const float*)d_in[4];
    const float* bo  = (const float*)d_in[5];
    float* out = (float*)d_out;
    float* ws  = (float*)d_ws;

    // reset row-group counters (R13 verbatim region, 64 B at 2 MB offset)
    hipMemsetAsync((char*)d_ws + (size_t)2 * BB * HH * 4, 0, NG * sizeof(int), stream);

    void* args[] = {(void*)&x, (void*)&Whx, (void*)&Whh, (void*)&Wph,
                    (void*)&bh, (void*)&bo, (void*)&out, (void*)&ws};
    hipLaunchCooperativeKernel((void*)rnn_persist, dim3(NG * NCT), dim3(NTH),
                               args, 0, stream);
}